// Round 21
// baseline (256.979 us; speedup 1.0000x reference)
//
#include <hip/hip_runtime.h>
#include <hip/hip_fp16.h>
#include <math.h>

#define NN 50000
#define DD 128
#define NCLS 40
#define EPSV 1e-8f
#define ELLCAP 64

typedef unsigned int uint4n __attribute__((ext_vector_type(4)));

__device__ __forceinline__ float waveReduceSum(float v) {
    for (int off = 32; off > 0; off >>= 1) v += __shfl_xor(v, off, 64);
    return v;
}

__device__ __forceinline__ float bcastlane0(float v) {
    return __int_as_float(__builtin_amdgcn_readfirstlane(__float_as_int(v)));
}

__device__ __forceinline__ float h_lo(unsigned int w) {
    return __half2float(__ushort_as_half((unsigned short)(w & 0xffffu)));
}
__device__ __forceinline__ float h_hi(unsigned int w) {
    return __half2float(__ushort_as_half((unsigned short)(w >> 16)));
}
__device__ __forceinline__ unsigned int h_pack(float a, float b) {
    return (unsigned int)__half_as_ushort(__float2half(a)) |
           ((unsigned int)__half_as_ushort(__float2half(b)) << 16);
}
__device__ __forceinline__ float fexp(float x) {
    return __builtin_amdgcn_exp2f(x * 1.44269504089f);
}
__device__ __forceinline__ float frcp(float x) { return __builtin_amdgcn_rcpf(x); }
__device__ __forceinline__ float frsq(float x) { return __builtin_amdgcn_rsqf(x); }

// ---------------- ELL build ----------------

__global__ void fill_ell_kernel(const int* __restrict__ erow, const int* __restrict__ ecol,
                                const float* __restrict__ ew, int* __restrict__ cnt,
                                unsigned int* __restrict__ ell, int E) {
    for (int e = blockIdx.x * blockDim.x + threadIdx.x; e < E; e += gridDim.x * blockDim.x) {
        int r = erow[e];
        int p = atomicAdd(&cnt[r], 1);
        if (p < ELLCAP) {
            unsigned int packed = (unsigned int)ecol[e] |
                ((unsigned int)__half_as_ushort(__float2half(ew[e])) << 16);
            ell[(long)r * ELLCAP + p] = packed;
        }
    }
}

__global__ void packwt_kernel(const float* __restrict__ W1, unsigned int* __restrict__ p1,
                              const float* __restrict__ W2, unsigned int* __restrict__ p2) {
    int b = blockIdx.x;
    const float* W = (b < 32) ? W1 : W2;
    unsigned int* P = (b < 32) ? p1 : p2;
    int a = (b & 31) * 256 + threadIdx.x;
    int pr = a >> 7;
    int rem = a & 127;
    int l = rem >> 1, kl = rem & 1;
    int k = 2 * pr + kl;
    P[a] = h_pack(W[(2 * l) * 128 + k], W[(2 * l + 1) * 128 + k]);
}

// ---------------- linear1: expmap + GEMM(fp16 W in LDS) + lorentz, fp16 out ----------------
#define RPW 8
__global__ __launch_bounds__(256, 4) void linear1_kernel(
    const float* __restrict__ X, const unsigned int* __restrict__ Wp,
    const float* __restrict__ bias, const float* __restrict__ logs,
    unsigned int* __restrict__ outh, int n)
{
    __shared__ unsigned int wS[8192];
    __shared__ float xrow[4][RPW * 128];
    int tid = threadIdx.x;
    int wid = tid >> 6, lane = tid & 63;
    #pragma unroll
    for (int i = 0; i < 8; ++i) {
        int idx = tid * 4 + i * 1024;
        *(uint4n*)(wS + idx) = *(const uint4n*)(Wp + idx);
    }
    __syncthreads();
    float2 bv = *(const float2*)(bias + 2 * lane);
    float sval = fminf(fexp(logs[0]), 10.f);
    float* xbase = xrow[wid];
    int nslabs = n / RPW;
    for (int slab = blockIdx.x * 4 + wid; slab < nslabs; slab += gridDim.x * 4) {
        int row0 = slab * RPW;
        #pragma unroll
        for (int r = 0; r < RPW; ++r) {
            int row = row0 + r;
            const float* src = X + (long)row * 127;
            float u0 = src[2 * lane];
            float u1 = (2 * lane + 1 < 127) ? src[2 * lane + 1] : 0.f;
            float ss = waveReduceSum(u0 * u0 + u1 * u1);
            float nrm = fmaxf(sqrtf(ss), EPSV);
            float ex = fexp(nrm), exn = fexp(-nrm);
            float ch = 0.5f * (ex + exn);
            float coef = 0.5f * (ex - exn) * frcp(nrm);
            if (lane == 0) xbase[r * 128] = ch;
            xbase[r * 128 + 1 + 2 * lane] = coef * u0;
            if (2 * lane + 1 < 127) xbase[r * 128 + 2 + 2 * lane] = coef * u1;
        }
        float2 acc[RPW];
        #pragma unroll
        for (int r = 0; r < RPW; ++r) acc[r] = make_float2(0.f, 0.f);
        #pragma unroll 4
        for (int k0 = 0; k0 < 128; k0 += 4) {
            uint2 wa = *(const uint2*)(wS + (k0 >> 1) * 128 + 2 * lane);
            uint2 wb = *(const uint2*)(wS + (k0 >> 1) * 128 + 128 + 2 * lane);
            float2 w0 = make_float2(h_lo(wa.x), h_hi(wa.x));
            float2 w1 = make_float2(h_lo(wa.y), h_hi(wa.y));
            float2 w2 = make_float2(h_lo(wb.x), h_hi(wb.x));
            float2 w3 = make_float2(h_lo(wb.y), h_hi(wb.y));
            #pragma unroll
            for (int r = 0; r < RPW; ++r) {
                float4 xq = *(const float4*)(xbase + r * 128 + k0);
                acc[r].x = fmaf(xq.x, w0.x, acc[r].x);
                acc[r].y = fmaf(xq.x, w0.y, acc[r].y);
                acc[r].x = fmaf(xq.y, w1.x, acc[r].x);
                acc[r].y = fmaf(xq.y, w1.y, acc[r].y);
                acc[r].x = fmaf(xq.z, w2.x, acc[r].x);
                acc[r].y = fmaf(xq.z, w2.y, acc[r].y);
                acc[r].x = fmaf(xq.w, w3.x, acc[r].x);
                acc[r].y = fmaf(xq.w, w3.y, acc[r].y);
            }
        }
        #pragma unroll
        for (int r = 0; r < RPW; ++r) {
            float ax = acc[r].x + bv.x;
            float ay = acc[r].y + bv.y;
            float t0 = __shfl(ax, 0, 64);
            float ssq = waveReduceSum(ax * ax + ay * ay);
            float timev = sval * frcp(1.f + fexp(-t0)) + 1.5f;
            float sq = fmaxf(ssq - t0 * t0, EPSV);
            float fac = sqrtf(fmaxf((timev * timev - 1.f) * frcp(sq), EPSV));
            float o0 = (lane == 0) ? timev : ax * fac;
            __builtin_nontemporal_store(h_pack(o0, ay * fac),
                                        &outh[(long)(row0 + r) * 64 + lane]);
        }
    }
}

// ---------------- linear2 ----------------
__global__ __launch_bounds__(256, 4) void linear2_kernel(
    const unsigned int* __restrict__ Xh, const unsigned int* __restrict__ Wp,
    const float* __restrict__ bias, const float* __restrict__ logs,
    unsigned int* __restrict__ outh, int n)
{
    __shared__ unsigned int wS[8192];
    __shared__ float xrow[4][RPW * 128];
    int tid = threadIdx.x;
    int wid = tid >> 6, lane = tid & 63;
    #pragma unroll
    for (int i = 0; i < 8; ++i) {
        int idx = tid * 4 + i * 1024;
        *(uint4n*)(wS + idx) = *(const uint4n*)(Wp + idx);
    }
    __syncthreads();
    float2 bv = *(const float2*)(bias + 2 * lane);
    float sval = fminf(fexp(logs[0]), 10.f);
    float* xbase = xrow[wid];
    int nslabs = n / RPW;
    for (int slab = blockIdx.x * 4 + wid; slab < nslabs; slab += gridDim.x * 4) {
        int row0 = slab * RPW;
        #pragma unroll
        for (int r = 0; r < RPW; ++r) {
            unsigned int u = __builtin_nontemporal_load(&Xh[(long)(row0 + r) * 64 + lane]);
            *(float2*)(xbase + r * 128 + 2 * lane) = make_float2(h_lo(u), h_hi(u));
        }
        float2 acc[RPW];
        #pragma unroll
        for (int r = 0; r < RPW; ++r) acc[r] = make_float2(0.f, 0.f);
        #pragma unroll 4
        for (int k0 = 0; k0 < 128; k0 += 4) {
            uint2 wa = *(const uint2*)(wS + (k0 >> 1) * 128 + 2 * lane);
            uint2 wb = *(const uint2*)(wS + (k0 >> 1) * 128 + 128 + 2 * lane);
            float2 w0 = make_float2(h_lo(wa.x), h_hi(wa.x));
            float2 w1 = make_float2(h_lo(wa.y), h_hi(wa.y));
            float2 w2 = make_float2(h_lo(wb.x), h_hi(wb.x));
            float2 w3 = make_float2(h_lo(wb.y), h_hi(wb.y));
            #pragma unroll
            for (int r = 0; r < RPW; ++r) {
                float4 xq = *(const float4*)(xbase + r * 128 + k0);
                acc[r].x = fmaf(xq.x, w0.x, acc[r].x);
                acc[r].y = fmaf(xq.x, w0.y, acc[r].y);
                acc[r].x = fmaf(xq.y, w1.x, acc[r].x);
                acc[r].y = fmaf(xq.y, w1.y, acc[r].y);
                acc[r].x = fmaf(xq.z, w2.x, acc[r].x);
                acc[r].y = fmaf(xq.z, w2.y, acc[r].y);
                acc[r].x = fmaf(xq.w, w3.x, acc[r].x);
                acc[r].y = fmaf(xq.w, w3.y, acc[r].y);
            }
        }
        #pragma unroll
        for (int r = 0; r < RPW; ++r) {
            float ax = acc[r].x + bv.x;
            float ay = acc[r].y + bv.y;
            float t0 = __shfl(ax, 0, 64);
            float ssq = waveReduceSum(ax * ax + ay * ay);
            float timev = sval * frcp(1.f + fexp(-t0)) + 1.5f;
            float sq = fmaxf(ssq - t0 * t0, EPSV);
            float fac = sqrtf(fmaxf((timev * timev - 1.f) * frcp(sq), EPSV));
            float o0 = (lane == 0) ? timev : ax * fac;
            __builtin_nontemporal_store(h_pack(o0, ay * fac),
                                        &outh[(long)(row0 + r) * 64 + lane]);
        }
    }
}

// ---------------- gather helpers: 4 rows/wave, 16 load-chains ----------------
// edge = packed uint: col (low 16) | fp16 weight (high 16)

#define GBODY(accs, eptr, idx)                                             \
    {                                                                      \
        unsigned int cw = eptr[idx];                                       \
        float w = h_hi(cw);                                                \
        uint4 xw = *(const uint4*)(Xh + (long)(cw & 0xffffu) * 64 + l16 * 4); \
        accs[0] = fmaf(w, h_lo(xw.x), accs[0]);                            \
        accs[1] = fmaf(w, h_hi(xw.x), accs[1]);                            \
        accs[2] = fmaf(w, h_lo(xw.y), accs[2]);                            \
        accs[3] = fmaf(w, h_hi(xw.y), accs[3]);                            \
        accs[4] = fmaf(w, h_lo(xw.z), accs[4]);                            \
        accs[5] = fmaf(w, h_hi(xw.z), accs[5]);                            \
        accs[6] = fmaf(w, h_lo(xw.w), accs[6]);                            \
        accs[7] = fmaf(w, h_hi(xw.w), accs[7]);                            \
    }

#define REDUCE8(accs)                                                      \
    _Pragma("unroll")                                                      \
    for (int q = 0; q < 8; ++q) {                                          \
        accs[q] += __shfl_xor(accs[q], 16, 64);                            \
        accs[q] += __shfl_xor(accs[q], 32, 64);                            \
    }

// all 4 groups stride all 4 rows' edges (predicated) -> 16 chains/wave
#define GATHER_QUAD()                                                      \
    int r0 = 4 * quad;                                                     \
    int c0 = min(cnt[r0 + 0], ELLCAP), c1 = min(cnt[r0 + 1], ELLCAP);      \
    int c2 = min(cnt[r0 + 2], ELLCAP), c3 = min(cnt[r0 + 3], ELLCAP);      \
    const unsigned int* e0 = ell + (long)(r0 + 0) * ELLCAP;                \
    const unsigned int* e1 = ell + (long)(r0 + 1) * ELLCAP;                \
    const unsigned int* e2 = ell + (long)(r0 + 2) * ELLCAP;                \
    const unsigned int* e3 = ell + (long)(r0 + 3) * ELLCAP;                \
    float a0[8] = {0,0,0,0,0,0,0,0};                                       \
    float a1[8] = {0,0,0,0,0,0,0,0};                                       \
    float a2[8] = {0,0,0,0,0,0,0,0};                                       \
    float a3[8] = {0,0,0,0,0,0,0,0};                                       \
    {                                                                      \
        int cmax = max(max(c0, c1), max(c2, c3));                          \
        for (int j = g; j < cmax; j += 4) {                                \
            if (j < c0) GBODY(a0, e0, j)                                   \
            if (j < c1) GBODY(a1, e1, j)                                   \
            if (j < c2) GBODY(a2, e2, j)                                   \
            if (j < c3) GBODY(a3, e3, j)                                   \
        }                                                                  \
    }                                                                      \
    REDUCE8(a0) REDUCE8(a1) REDUCE8(a2) REDUCE8(a3)

#define SS16(ss)                                                           \
    ss += __shfl_xor(ss, 1, 64); ss += __shfl_xor(ss, 2, 64);              \
    ss += __shfl_xor(ss, 4, 64); ss += __shfl_xor(ss, 8, 64);

#define ROWNORM(accs, invv)                                                \
    float invv;                                                            \
    {                                                                      \
        float ss = accs[0]*accs[0]+accs[1]*accs[1]+accs[2]*accs[2]+accs[3]*accs[3] \
                 + accs[4]*accs[4]+accs[5]*accs[5]+accs[6]*accs[6]+accs[7]*accs[7]; \
        SS16(ss)                                                           \
        float t0 = bcastlane0(accs[0]);                                    \
        invv = frsq(fmaxf(fabsf(2.f * t0 * t0 - ss), EPSV));               \
    }

// ---------------- agg1 + lorentz-normalize + relu -> fp16 ----------------
__global__ __launch_bounds__(256, 8) void gather_norm_kernel(
    const unsigned int* __restrict__ Xh, const int* __restrict__ cnt,
    const unsigned int* __restrict__ ell, unsigned int* __restrict__ outh, int n)
{
    int wid = threadIdx.x >> 6, lane = threadIdx.x & 63;
    int g = lane >> 4, l16 = lane & 15;
    int nquads = n >> 2;    // 12500
    for (int quad = blockIdx.x * 4 + wid; quad < nquads; quad += gridDim.x * 4) {
        GATHER_QUAD()
        ROWNORM(a0, inv0)
        ROWNORM(a1, inv1)
        ROWNORM(a2, inv2)
        ROWNORM(a3, inv3)
        // group g writes row r0+g (relu + fp16 pack)
        uint4n o;
        if (g == 0) {
            o.x = h_pack(fmaxf(a0[0]*inv0,0.f), fmaxf(a0[1]*inv0,0.f));
            o.y = h_pack(fmaxf(a0[2]*inv0,0.f), fmaxf(a0[3]*inv0,0.f));
            o.z = h_pack(fmaxf(a0[4]*inv0,0.f), fmaxf(a0[5]*inv0,0.f));
            o.w = h_pack(fmaxf(a0[6]*inv0,0.f), fmaxf(a0[7]*inv0,0.f));
        } else if (g == 1) {
            o.x = h_pack(fmaxf(a1[0]*inv1,0.f), fmaxf(a1[1]*inv1,0.f));
            o.y = h_pack(fmaxf(a1[2]*inv1,0.f), fmaxf(a1[3]*inv1,0.f));
            o.z = h_pack(fmaxf(a1[4]*inv1,0.f), fmaxf(a1[5]*inv1,0.f));
            o.w = h_pack(fmaxf(a1[6]*inv1,0.f), fmaxf(a1[7]*inv1,0.f));
        } else if (g == 2) {
            o.x = h_pack(fmaxf(a2[0]*inv2,0.f), fmaxf(a2[1]*inv2,0.f));
            o.y = h_pack(fmaxf(a2[2]*inv2,0.f), fmaxf(a2[3]*inv2,0.f));
            o.z = h_pack(fmaxf(a2[4]*inv2,0.f), fmaxf(a2[5]*inv2,0.f));
            o.w = h_pack(fmaxf(a2[6]*inv2,0.f), fmaxf(a2[7]*inv2,0.f));
        } else {
            o.x = h_pack(fmaxf(a3[0]*inv3,0.f), fmaxf(a3[1]*inv3,0.f));
            o.y = h_pack(fmaxf(a3[2]*inv3,0.f), fmaxf(a3[3]*inv3,0.f));
            o.z = h_pack(fmaxf(a3[4]*inv3,0.f), fmaxf(a3[5]*inv3,0.f));
            o.w = h_pack(fmaxf(a3[6]*inv3,0.f), fmaxf(a3[7]*inv3,0.f));
        }
        __builtin_nontemporal_store(o, (uint4n*)(outh + (long)(r0 + g) * 64 + l16 * 4));
    }
}

// ---------------- agg2 + lorentz-normalize + sign-flip + logits ----------------
__global__ __launch_bounds__(256, 8) void gather_logits_kernel(
    const unsigned int* __restrict__ Xh, const int* __restrict__ cnt,
    const unsigned int* __restrict__ ell,
    const float* __restrict__ cls, const float* __restrict__ cbias,
    float* __restrict__ outp, int n)
{
    __shared__ unsigned int clsP[NCLS * 66];
    __shared__ float cbS[NCLS];
    __shared__ float xsrow[4][4][128];      // 4 waves x 4 rows x 128 = 8KB
    int tid = threadIdx.x;
    for (int idx = tid; idx < NCLS * 64; idx += 256) {
        int c = idx >> 6, kk = idx & 63;
        clsP[c * 66 + kk] = h_pack(cls[c * 128 + 2 * kk], cls[c * 128 + 2 * kk + 1]);
    }
    if (tid < NCLS) cbS[tid] = cbias[tid];
    __syncthreads();
    int wid = tid >> 6, lane = tid & 63;
    int g = lane >> 4, l16 = lane & 15;
    float* xs = &xsrow[wid][0][0];
    int nquads = n >> 2;
    for (int quad = blockIdx.x * 4 + wid; quad < nquads; quad += gridDim.x * 4) {
        GATHER_QUAD()
        ROWNORM(a0, inv0)
        ROWNORM(a1, inv1)
        ROWNORM(a2, inv2)
        ROWNORM(a3, inv3)
        // group g stages row g into LDS (sign-flip on element 0)
        float* xp = xs + g * 128 + l16 * 8;
        if (g == 0) {
            float v0 = a0[0] * inv0; if (l16 == 0) v0 = -v0;
            *(float4*)xp       = make_float4(v0, a0[1]*inv0, a0[2]*inv0, a0[3]*inv0);
            *(float4*)(xp + 4) = make_float4(a0[4]*inv0, a0[5]*inv0, a0[6]*inv0, a0[7]*inv0);
        } else if (g == 1) {
            float v0 = a1[0] * inv1; if (l16 == 0) v0 = -v0;
            *(float4*)xp       = make_float4(v0, a1[1]*inv1, a1[2]*inv1, a1[3]*inv1);
            *(float4*)(xp + 4) = make_float4(a1[4]*inv1, a1[5]*inv1, a1[6]*inv1, a1[7]*inv1);
        } else if (g == 2) {
            float v0 = a2[0] * inv2; if (l16 == 0) v0 = -v0;
            *(float4*)xp       = make_float4(v0, a2[1]*inv2, a2[2]*inv2, a2[3]*inv2);
            *(float4*)(xp + 4) = make_float4(a2[4]*inv2, a2[5]*inv2, a2[6]*inv2, a2[7]*inv2);
        } else {
            float v0 = a3[0] * inv3; if (l16 == 0) v0 = -v0;
            *(float4*)xp       = make_float4(v0, a3[1]*inv3, a3[2]*inv3, a3[3]*inv3);
            *(float4*)(xp + 4) = make_float4(a3[4]*inv3, a3[5]*inv3, a3[6]*inv3, a3[7]*inv3);
        }
        // wave-private LDS: within-wave ordering, no barrier
        if (lane < NCLS) {
            float d0 = 0.f, d1 = 0.f, d2 = 0.f, d3 = 0.f;
            const unsigned int* cp = clsP + lane * 66;
            #pragma unroll 4
            for (int kk = 0; kk < 64; ++kk) {
                unsigned int u = cp[kk];
                float cc0 = h_lo(u), cc1 = h_hi(u);
                float2 x0 = *(const float2*)(xs + 0 * 128 + 2 * kk);
                float2 x1 = *(const float2*)(xs + 1 * 128 + 2 * kk);
                float2 x2 = *(const float2*)(xs + 2 * 128 + 2 * kk);
                float2 x3 = *(const float2*)(xs + 3 * 128 + 2 * kk);
                d0 = fmaf(cc0, x0.x, d0); d0 = fmaf(cc1, x0.y, d0);
                d1 = fmaf(cc0, x1.x, d1); d1 = fmaf(cc1, x1.y, d1);
                d2 = fmaf(cc0, x2.x, d2); d2 = fmaf(cc1, x2.y, d2);
                d3 = fmaf(cc0, x3.x, d3); d3 = fmaf(cc1, x3.y, d3);
            }
            float cb = cbS[lane];
            outp[(long)(r0 + 0) * NCLS + lane] = 2.f + 2.f * d0 + cb;
            outp[(long)(r0 + 1) * NCLS + lane] = 2.f + 2.f * d1 + cb;
            outp[(long)(r0 + 2) * NCLS + lane] = 2.f + 2.f * d2 + cb;
            outp[(long)(r0 + 3) * NCLS + lane] = 2.f + 2.f * d3 + cb;
        }
    }
}

// ---------------- launch ----------------

extern "C" void kernel_launch(void* const* d_in, const int* in_sizes, int n_in,
                              void* d_out, int out_size, void* d_ws, size_t ws_size,
                              hipStream_t stream) {
    const float* node_feat = (const float*)d_in[0];
    const float* W1   = (const float*)d_in[1];
    const float* b1   = (const float*)d_in[2];
    const float* s1   = (const float*)d_in[3];
    const float* W2   = (const float*)d_in[4];
    const float* b2   = (const float*)d_in[5];
    const float* s2   = (const float*)d_in[6];
    const float* cls  = (const float*)d_in[7];
    const float* cb   = (const float*)d_in[8];
    const float* ew   = (const float*)d_in[9];
    const int*   erow = (const int*)d_in[10];
    const int*   ecol = (const int*)d_in[11];
    float* outp = (float*)d_out;

    const int n = NN;
    const int E = in_sizes[9];

    unsigned int* bufH1 = (unsigned int*)d_ws;
    unsigned int* bufH2 = bufH1 + (size_t)NN * 64;
    int*   cnt    = (int*)(bufH2 + (size_t)NN * 64);
    unsigned int* ell = (unsigned int*)(cnt + NN);
    unsigned int* wp1 = ell + (size_t)NN * ELLCAP;
    unsigned int* wp2 = wp1 + 128 * 64;

    (void)hipMemsetAsync(cnt, 0, (size_t)NN * sizeof(int), stream);
    packwt_kernel<<<64, 256, 0, stream>>>(W1, wp1, W2, wp2);
    fill_ell_kernel<<<2048, 256, 0, stream>>>(erow, ecol, ew, cnt, ell, E);

    const int LGRID = (n / RPW + 3) / 4;        // 1563
    const int QGRID = ((n >> 2) + 3) / 4;       // 3125 (row quads)

    linear1_kernel<<<LGRID, 256, 0, stream>>>(node_feat, wp1, b1, s1, bufH1, n);
    gather_norm_kernel<<<QGRID, 256, 0, stream>>>(bufH1, cnt, ell, bufH2, n);
    linear2_kernel<<<LGRID, 256, 0, stream>>>(bufH2, wp2, b2, s2, bufH1, n);
    gather_logits_kernel<<<QGRID, 256, 0, stream>>>(bufH1, cnt, ell, cls, cb, outp, n);
}